// Round 1
// baseline (335.103 us; speedup 1.0000x reference)
//
#include <hip/hip_runtime.h>
#include <hip/hip_bf16.h>

// Problem constants
static constexpr int kB   = 8;
static constexpr int kP   = 196;
static constexpr int kL   = 80;
static constexpr int kD1  = 2048;
static constexpr int kD2  = 300;
static constexpr int kATT = 1024;
static constexpr int kM   = kB * kP;   // 1568 rows of p1
static constexpr int kR2  = kB * kL;   // 640 rows of p2

// tanh(x) = 1 - 2/(exp2(x*2*log2(e)) + 1)   (exact at 0, saturates correctly)
__device__ __forceinline__ float fast_tanh(float x) {
    float e = __builtin_amdgcn_exp2f(x * 2.8853900817779268f);
    return 1.0f - 2.0f * __builtin_amdgcn_rcpf(e + 1.0f);
}

// ---------------------------------------------------------------------------
// v[a] = sum_c wt[c]*Wh[c,a];  beta = dot(wt,bh) + bt
// grid (4, 16): x = a-chunk of 256, y = c-slice of 64. v/beta pre-zeroed.
// ---------------------------------------------------------------------------
__global__ __launch_bounds__(256) void vbeta_kernel(
        const float* __restrict__ Wh, const float* __restrict__ wt,
        const float* __restrict__ bh, const float* __restrict__ bt,
        float* __restrict__ v, float* __restrict__ beta) {
    const int a  = blockIdx.x * 256 + threadIdx.x;
    const int c0 = blockIdx.y * 64;
    float acc = 0.0f;
    #pragma unroll 8
    for (int c = c0; c < c0 + 64; ++c)
        acc = fmaf(wt[c], Wh[(size_t)c * kATT + a], acc);
    atomicAdd(&v[a], acc);

    if (blockIdx.x == 0 && threadIdx.x < 64) {   // wave 0 of this block
        int c = c0 + threadIdx.x;
        float pb = wt[c] * bh[c];
        #pragma unroll
        for (int off = 32; off > 0; off >>= 1)
            pb += __shfl_down(pb, off, 64);
        if (threadIdx.x == 0) {
            if (blockIdx.y == 0) pb += bt[0];
            atomicAdd(beta, pb);
        }
    }
}

// ---------------------------------------------------------------------------
// p2[r, a] = sum_d x2[r, d] * W2[a, d]   (r over B*L = 640, K = 300)
// grid 80 blocks: each block does 8 rows x all 1024 a. x2 rows staged in LDS.
// ---------------------------------------------------------------------------
__global__ __launch_bounds__(256) void p2_kernel(
        const float* __restrict__ x2, const float* __restrict__ W2,
        float* __restrict__ p2o) {
    __shared__ float xs[8 * kD2];            // 9600 B, rows 16B-aligned (1200B)
    const int r0  = blockIdx.x * 8;
    const int tid = threadIdx.x;
    for (int i = tid; i < 8 * kD2; i += 256)
        xs[i] = x2[(size_t)r0 * kD2 + i];
    __syncthreads();

    float acc[4][8] = {};
    for (int d4 = 0; d4 < kD2 / 4; ++d4) {   // 75 float4 steps
        float4 xv[8];
        #pragma unroll
        for (int r = 0; r < 8; ++r)
            xv[r] = *(const float4*)&xs[r * kD2 + d4 * 4];  // broadcast reads
        #pragma unroll
        for (int j = 0; j < 4; ++j) {
            int a = tid + j * 256;
            float4 w = *(const float4*)&W2[(size_t)a * kD2 + d4 * 4];
            #pragma unroll
            for (int r = 0; r < 8; ++r) {
                acc[j][r] = fmaf(w.x, xv[r].x, acc[j][r]);
                acc[j][r] = fmaf(w.y, xv[r].y, acc[j][r]);
                acc[j][r] = fmaf(w.z, xv[r].z, acc[j][r]);
                acc[j][r] = fmaf(w.w, xv[r].w, acc[j][r]);
            }
        }
    }
    #pragma unroll
    for (int j = 0; j < 4; ++j)
        #pragma unroll
        for (int r = 0; r < 8; ++r)
            p2o[(size_t)(r0 + r) * kATT + tid + j * 256] = acc[j][r];
}

// ---------------------------------------------------------------------------
// p1[m, n] = sum_k x1[m, k] * W1[n, k]   (M=1568, N=1024, K=2048) fp32 tiled
// 64x64 tile, 256 threads, 4x4 micro-tile, K-chunks of 16 staged k-major.
// ---------------------------------------------------------------------------
__global__ __launch_bounds__(256) void p1_kernel(
        const float* __restrict__ x1, const float* __restrict__ W1,
        float* __restrict__ p1o) {
    __shared__ float As[16 * 68];            // [k][m], stride 68 (16B-aligned)
    __shared__ float Bs[16 * 68];            // [k][n]
    const int m0  = blockIdx.x * 64;
    const int n0  = blockIdx.y * 64;
    const int tid = threadIdx.x;
    const int tx  = tid & 15, ty = tid >> 4;
    const int lm  = tid >> 2;                // 0..63
    const int lk  = (tid & 3) * 4;           // 0,4,8,12
    const int arow = min(m0 + lm, kM - 1);   // clamp ragged M edge
    const int brow = n0 + lm;                // N = 1024 exact

    float acc[4][4] = {};
    for (int k0 = 0; k0 < kD1; k0 += 16) {
        float4 av = *(const float4*)(x1 + (size_t)arow * kD1 + k0 + lk);
        float4 bv = *(const float4*)(W1 + (size_t)brow * kD1 + k0 + lk);
        __syncthreads();
        As[(lk + 0) * 68 + lm] = av.x;  As[(lk + 1) * 68 + lm] = av.y;
        As[(lk + 2) * 68 + lm] = av.z;  As[(lk + 3) * 68 + lm] = av.w;
        Bs[(lk + 0) * 68 + lm] = bv.x;  Bs[(lk + 1) * 68 + lm] = bv.y;
        Bs[(lk + 2) * 68 + lm] = bv.z;  Bs[(lk + 3) * 68 + lm] = bv.w;
        __syncthreads();
        #pragma unroll
        for (int k = 0; k < 16; ++k) {
            float4 a4 = *(const float4*)&As[k * 68 + ty * 4];
            float4 b4 = *(const float4*)&Bs[k * 68 + tx * 4];
            float am[4] = {a4.x, a4.y, a4.z, a4.w};
            float bn[4] = {b4.x, b4.y, b4.z, b4.w};
            #pragma unroll
            for (int i = 0; i < 4; ++i)
                #pragma unroll
                for (int j = 0; j < 4; ++j)
                    acc[i][j] = fmaf(am[i], bn[j], acc[i][j]);
        }
    }
    #pragma unroll
    for (int i = 0; i < 4; ++i) {
        int m = m0 + ty * 4 + i;
        if (m < kM) {
            float4 o = make_float4(acc[i][0], acc[i][1], acc[i][2], acc[i][3]);
            *(float4*)(p1o + (size_t)m * kATT + n0 + tx * 4) = o;
        }
    }
}

// ---------------------------------------------------------------------------
// alpha[b,l,p] = sum_a v[a]*tanh(p1[b,p,a]*p2[b,l,a]) + beta
// grid (13, 5, 8): 16x16 (p,l) tile per block, a staged in chunks of 128.
// ---------------------------------------------------------------------------
__global__ __launch_bounds__(256) void alpha_kernel(
        const float* __restrict__ p1, const float* __restrict__ p2,
        const float* __restrict__ v, const float* __restrict__ beta,
        float* __restrict__ out) {
    __shared__ float vs[kATT];               // 4 KB
    __shared__ float p1s[16 * 132];          // stride 132 breaks bank aliasing
    __shared__ float p2s[16 * 132];
    const int b   = blockIdx.z;
    const int p0  = blockIdx.x * 16;
    const int l0  = blockIdx.y * 16;
    const int tid = threadIdx.x;
    const int tp  = tid & 15;                // p across lanes -> coalesced store
    const int tl  = tid >> 4;

    for (int i = tid; i < kATT; i += 256) vs[i] = v[i];

    float acc = 0.0f;
    for (int a0 = 0; a0 < kATT; a0 += 128) {
        __syncthreads();
        #pragma unroll
        for (int t = 0; t < 2; ++t) {
            int idx = tid + t * 256;         // 0..511 float4 slots
            int row = idx >> 5;              // 0..15
            int c4  = (idx & 31) * 4;        // 0..124
            int gr1 = min(b * kP + p0 + row, kM - 1);   // clamp ragged p edge
            float4 u = *(const float4*)(p1 + (size_t)gr1 * kATT + a0 + c4);
            *(float4*)&p1s[row * 132 + c4] = u;
            int gr2 = b * kL + l0 + row;     // always in range
            float4 w = *(const float4*)(p2 + (size_t)gr2 * kATT + a0 + c4);
            *(float4*)&p2s[row * 132 + c4] = w;
        }
        __syncthreads();
        #pragma unroll
        for (int a4 = 0; a4 < 32; ++a4) {
            float4 u  = *(const float4*)&p1s[tp * 132 + a4 * 4];
            float4 w  = *(const float4*)&p2s[tl * 132 + a4 * 4];
            float4 vv = *(const float4*)&vs[a0 + a4 * 4];
            acc = fmaf(vv.x, fast_tanh(u.x * w.x), acc);
            acc = fmaf(vv.y, fast_tanh(u.y * w.y), acc);
            acc = fmaf(vv.z, fast_tanh(u.z * w.z), acc);
            acc = fmaf(vv.w, fast_tanh(u.w * w.w), acc);
        }
    }
    int p = p0 + tp;
    if (p < kP)
        out[((size_t)b * kL + l0 + tl) * kP + p] = acc + beta[0];
}

// ---------------------------------------------------------------------------
extern "C" void kernel_launch(void* const* d_in, const int* in_sizes, int n_in,
                              void* d_out, int out_size, void* d_ws, size_t ws_size,
                              hipStream_t stream) {
    const float* x1 = (const float*)d_in[0];
    const float* x2 = (const float*)d_in[1];
    const float* W1 = (const float*)d_in[2];
    const float* W2 = (const float*)d_in[3];
    const float* Wh = (const float*)d_in[4];
    const float* bh = (const float*)d_in[5];
    const float* wt = (const float*)d_in[6];
    const float* bt = (const float*)d_in[7];
    float* out = (float*)d_out;

    // workspace layout (floats): v[1024] | beta[1] pad to 1088 | p2[640*1024] | p1[1568*1024]
    float* ws   = (float*)d_ws;
    float* v    = ws;
    float* beta = ws + 1024;
    float* p2w  = ws + 1088;
    float* p1w  = ws + 1088 + (size_t)kR2 * kATT;
    // total: (1088 + 655360 + 1605632) * 4 = ~8.6 MB  (<< ws_size)

    // zero v + beta (ws is poisoned 0xAA before every call)
    hipMemsetAsync(ws, 0, 1088 * sizeof(float), stream);

    vbeta_kernel<<<dim3(4, 16), 256, 0, stream>>>(Wh, wt, bh, bt, v, beta);
    p2_kernel<<<dim3(kR2 / 8), 256, 0, stream>>>(x2, W2, p2w);
    p1_kernel<<<dim3((kM + 63) / 64, kATT / 64), 256, 0, stream>>>(x1, W1, p1w);
    alpha_kernel<<<dim3((kP + 15) / 16, kL / 16, kB), 256, 0, stream>>>(p1w, p2w, v, beta, out);
}

// Round 2
// 240.497 us; speedup vs baseline: 1.3934x; 1.3934x over previous
//
#include <hip/hip_runtime.h>
#include <hip/hip_bf16.h>

// Problem constants
static constexpr int kB   = 8;
static constexpr int kP   = 196;
static constexpr int kL   = 80;
static constexpr int kD1  = 2048;
static constexpr int kD2  = 300;
static constexpr int kATT = 1024;
static constexpr int kM   = kB * kP;   // 1568 rows of p1
static constexpr int kR2  = kB * kL;   // 640 rows of p2

// tanh(x) = 1 - 2/(exp2(x*2*log2(e)) + 1)   (exact at 0, saturates correctly)
__device__ __forceinline__ float fast_tanh(float x) {
    float e = __builtin_amdgcn_exp2f(x * 2.8853900817779268f);
    return 1.0f - 2.0f * __builtin_amdgcn_rcpf(e + 1.0f);
}

// fp32 -> bf16 round-to-nearest-even (inputs are finite; skip NaN path)
__device__ __forceinline__ unsigned short f2bf(float x) {
    union { float f; unsigned int u; } c; c.f = x;
    unsigned int r = c.u + 0x7fffu + ((c.u >> 16) & 1u);
    return (unsigned short)(r >> 16);
}

typedef __attribute__((ext_vector_type(8))) short  bf16x8;
typedef __attribute__((ext_vector_type(4))) float  f32x4;

__device__ __forceinline__ void load_lds16(const void* g, void* l) {
    __builtin_amdgcn_global_load_lds(
        (const __attribute__((address_space(1))) void*)g,
        (__attribute__((address_space(3))) void*)l, 16, 0, 0);
}

// ---------------------------------------------------------------------------
// Cast x1 (kM x kD1) and W1 (kATT x kD1) fp32 -> bf16, vectorized 4-wide.
// ---------------------------------------------------------------------------
__global__ __launch_bounds__(256) void cast_kernel(
        const float* __restrict__ x1, unsigned short* __restrict__ x1b,
        const float* __restrict__ W1, unsigned short* __restrict__ W1b) {
    const int n1 = kM * kD1 / 4;           // float4 count of x1
    const int n2 = kATT * kD1 / 4;         // float4 count of W1
    int i = blockIdx.x * 256 + threadIdx.x;
    if (i < n1) {
        float4 f = ((const float4*)x1)[i];
        ushort4 o = { f2bf(f.x), f2bf(f.y), f2bf(f.z), f2bf(f.w) };
        ((ushort4*)x1b)[i] = o;
    } else if (i - n1 < n2) {
        int j = i - n1;
        float4 f = ((const float4*)W1)[j];
        ushort4 o = { f2bf(f.x), f2bf(f.y), f2bf(f.z), f2bf(f.w) };
        ((ushort4*)W1b)[j] = o;
    }
}

// ---------------------------------------------------------------------------
// v[a] = sum_c wt[c]*Wh[c,a];  beta = dot(wt,bh) + bt
// ---------------------------------------------------------------------------
__global__ __launch_bounds__(256) void vbeta_kernel(
        const float* __restrict__ Wh, const float* __restrict__ wt,
        const float* __restrict__ bh, const float* __restrict__ bt,
        float* __restrict__ v, float* __restrict__ beta) {
    const int a  = blockIdx.x * 256 + threadIdx.x;
    const int c0 = blockIdx.y * 64;
    float acc = 0.0f;
    #pragma unroll 8
    for (int c = c0; c < c0 + 64; ++c)
        acc = fmaf(wt[c], Wh[(size_t)c * kATT + a], acc);
    atomicAdd(&v[a], acc);

    if (blockIdx.x == 0 && threadIdx.x < 64) {
        int c = c0 + threadIdx.x;
        float pb = wt[c] * bh[c];
        #pragma unroll
        for (int off = 32; off > 0; off >>= 1)
            pb += __shfl_down(pb, off, 64);
        if (threadIdx.x == 0) {
            if (blockIdx.y == 0) pb += bt[0];
            atomicAdd(beta, pb);
        }
    }
}

// ---------------------------------------------------------------------------
// p2[r, a] = sum_d x2[r, d] * W2[a, d]   (r over B*L = 640, K = 300)
// ---------------------------------------------------------------------------
__global__ __launch_bounds__(256) void p2_kernel(
        const float* __restrict__ x2, const float* __restrict__ W2,
        float* __restrict__ p2o) {
    __shared__ float xs[8 * kD2];
    const int r0  = blockIdx.x * 8;
    const int tid = threadIdx.x;
    for (int i = tid; i < 8 * kD2; i += 256)
        xs[i] = x2[(size_t)r0 * kD2 + i];
    __syncthreads();

    float acc[4][8] = {};
    for (int d4 = 0; d4 < kD2 / 4; ++d4) {
        float4 xv[8];
        #pragma unroll
        for (int r = 0; r < 8; ++r)
            xv[r] = *(const float4*)&xs[r * kD2 + d4 * 4];
        #pragma unroll
        for (int j = 0; j < 4; ++j) {
            int a = tid + j * 256;
            float4 w = *(const float4*)&W2[(size_t)a * kD2 + d4 * 4];
            #pragma unroll
            for (int r = 0; r < 8; ++r) {
                acc[j][r] = fmaf(w.x, xv[r].x, acc[j][r]);
                acc[j][r] = fmaf(w.y, xv[r].y, acc[j][r]);
                acc[j][r] = fmaf(w.z, xv[r].z, acc[j][r]);
                acc[j][r] = fmaf(w.w, xv[r].w, acc[j][r]);
            }
        }
    }
    #pragma unroll
    for (int j = 0; j < 4; ++j)
        #pragma unroll
        for (int r = 0; r < 8; ++r)
            p2o[(size_t)(r0 + r) * kATT + tid + j * 256] = acc[j][r];
}

// ---------------------------------------------------------------------------
// p1[m,n] = sum_k x1b[m,k]*W1b[n,k]  bf16 MFMA, 64x64 tile, BK=32, 4 waves.
// Wave w computes the 32x32 quadrant (w>>1, w&1) as 2x2 MFMA 16x16 tiles.
// LDS: [row][k] k-major, 64B rows (global_load_lds lane-contiguous layout).
// ---------------------------------------------------------------------------
__global__ __launch_bounds__(256) void p1_mfma_kernel(
        const unsigned short* __restrict__ Ab,   // x1b  kM x kD1
        const unsigned short* __restrict__ Bb,   // W1b  kATT x kD1
        float* __restrict__ p1o) {
    __shared__ unsigned short As[64 * 32];   // 4 KB, row stride 64 B
    __shared__ unsigned short Bs[64 * 32];   // 4 KB
    const int m0   = blockIdx.x * 64;
    const int n0   = blockIdx.y * 64;
    const int tid  = threadIdx.x;
    const int lane = tid & 63;
    const int wv   = tid >> 6;
    const int mh   = (wv >> 1) * 32;         // wave's m-quadrant
    const int nh   = (wv & 1) * 32;          // wave's n-quadrant

    // staging assignment: chunk c = tid covers (row = c>>2, kchunk = c&3)
    const int srow = tid >> 2;
    const int skc  = (tid & 3) * 8;          // element offset along k
    const int arow = min(m0 + srow, kM - 1); // clamp ragged M edge
    const int brow = n0 + srow;              // N exact

    f32x4 acc[2][2] = {};
    for (int k0 = 0; k0 < kD1; k0 += 32) {
        load_lds16(Ab + (size_t)arow * kD1 + k0 + skc, (char*)As + tid * 16);
        load_lds16(Bb + (size_t)brow * kD1 + k0 + skc, (char*)Bs + tid * 16);
        __syncthreads();                      // drain loads, LDS ready

        bf16x8 af[2], bf[2];
        #pragma unroll
        for (int i = 0; i < 2; ++i) {
            int r = mh + i * 16 + (lane & 15);
            af[i] = *(const bf16x8*)((const char*)As + r * 64 + (lane >> 4) * 16);
        }
        #pragma unroll
        for (int j = 0; j < 2; ++j) {
            int r = nh + j * 16 + (lane & 15);
            bf[j] = *(const bf16x8*)((const char*)Bs + r * 64 + (lane >> 4) * 16);
        }
        #pragma unroll
        for (int i = 0; i < 2; ++i)
            #pragma unroll
            for (int j = 0; j < 2; ++j)
                acc[i][j] = __builtin_amdgcn_mfma_f32_16x16x32_bf16(
                                af[i], bf[j], acc[i][j], 0, 0, 0);
        __syncthreads();                      // compute done before overwrite
    }

    // C/D layout: col = lane&15, row = (lane>>4)*4 + reg   [m89/m91 verified]
    #pragma unroll
    for (int i = 0; i < 2; ++i)
        #pragma unroll
        for (int j = 0; j < 2; ++j)
            #pragma unroll
            for (int r = 0; r < 4; ++r) {
                int m = m0 + mh + i * 16 + (lane >> 4) * 4 + r;
                int n = n0 + nh + j * 16 + (lane & 15);
                if (m < kM) p1o[(size_t)m * kATT + n] = acc[i][j][r];
            }
}

// ---------------------------------------------------------------------------
// alpha[b,l,p] = sum_a v[a]*tanh(p1[b,p,a]*p2[b,l,a]) + beta
// ---------------------------------------------------------------------------
__global__ __launch_bounds__(256) void alpha_kernel(
        const float* __restrict__ p1, const float* __restrict__ p2,
        const float* __restrict__ v, const float* __restrict__ beta,
        float* __restrict__ out) {
    __shared__ float vs[kATT];
    __shared__ float p1s[16 * 132];
    __shared__ float p2s[16 * 132];
    const int b   = blockIdx.z;
    const int p0  = blockIdx.x * 16;
    const int l0  = blockIdx.y * 16;
    const int tid = threadIdx.x;
    const int tp  = tid & 15;
    const int tl  = tid >> 4;

    for (int i = tid; i < kATT; i += 256) vs[i] = v[i];

    float acc = 0.0f;
    for (int a0 = 0; a0 < kATT; a0 += 128) {
        __syncthreads();
        #pragma unroll
        for (int t = 0; t < 2; ++t) {
            int idx = tid + t * 256;
            int row = idx >> 5;
            int c4  = (idx & 31) * 4;
            int gr1 = min(b * kP + p0 + row, kM - 1);
            float4 u = *(const float4*)(p1 + (size_t)gr1 * kATT + a0 + c4);
            *(float4*)&p1s[row * 132 + c4] = u;
            int gr2 = b * kL + l0 + row;
            float4 w = *(const float4*)(p2 + (size_t)gr2 * kATT + a0 + c4);
            *(float4*)&p2s[row * 132 + c4] = w;
        }
        __syncthreads();
        #pragma unroll
        for (int a4 = 0; a4 < 32; ++a4) {
            float4 u  = *(const float4*)&p1s[tp * 132 + a4 * 4];
            float4 w  = *(const float4*)&p2s[tl * 132 + a4 * 4];
            float4 vv = *(const float4*)&vs[a0 + a4 * 4];
            acc = fmaf(vv.x, fast_tanh(u.x * w.x), acc);
            acc = fmaf(vv.y, fast_tanh(u.y * w.y), acc);
            acc = fmaf(vv.z, fast_tanh(u.z * w.z), acc);
            acc = fmaf(vv.w, fast_tanh(u.w * w.w), acc);
        }
    }
    int p = p0 + tp;
    if (p < kP)
        out[((size_t)b * kL + l0 + tl) * kP + p] = acc + beta[0];
}

// ---------------------------------------------------------------------------
extern "C" void kernel_launch(void* const* d_in, const int* in_sizes, int n_in,
                              void* d_out, int out_size, void* d_ws, size_t ws_size,
                              hipStream_t stream) {
    const float* x1 = (const float*)d_in[0];
    const float* x2 = (const float*)d_in[1];
    const float* W1 = (const float*)d_in[2];
    const float* W2 = (const float*)d_in[3];
    const float* Wh = (const float*)d_in[4];
    const float* bh = (const float*)d_in[5];
    const float* wt = (const float*)d_in[6];
    const float* bt = (const float*)d_in[7];
    float* out = (float*)d_out;

    // workspace layout (floats):
    // v[1024] | beta[1].. pad 1088 | p2w[640*1024] | p1w[1568*1024] | bf16 area
    float* ws   = (float*)d_ws;
    float* v    = ws;
    float* beta = ws + 1024;
    float* p2w  = ws + 1088;
    float* p1w  = p2w + (size_t)kR2 * kATT;
    unsigned short* x1b = (unsigned short*)(p1w + (size_t)kM * kATT);
    unsigned short* W1b = x1b + (size_t)kM * kD1;
    // total ≈ 8.6 MB fp32 + 10.6 MB bf16 ≈ 19.2 MB

    hipMemsetAsync(ws, 0, 1088 * sizeof(float), stream);

    {   // cast x1 + W1 to bf16
        int n4 = (kM * kD1 + kATT * kD1) / 4;
        cast_kernel<<<dim3((n4 + 255) / 256), 256, 0, stream>>>(x1, x1b, W1, W1b);
    }
    vbeta_kernel<<<dim3(4, 16), 256, 0, stream>>>(Wh, wt, bh, bt, v, beta);
    p2_kernel<<<dim3(kR2 / 8), 256, 0, stream>>>(x2, W2, p2w);
    p1_mfma_kernel<<<dim3((kM + 63) / 64, kATT / 64), 256, 0, stream>>>(x1b, W1b, p1w);
    alpha_kernel<<<dim3((kP + 15) / 16, kL / 16, kB), 256, 0, stream>>>(p1w, p2w, v, beta, out);
}

// Round 3
// 183.293 us; speedup vs baseline: 1.8282x; 1.3121x over previous
//
#include <hip/hip_runtime.h>
#include <hip/hip_bf16.h>

// Problem constants
static constexpr int kB   = 8;
static constexpr int kP   = 196;
static constexpr int kL   = 80;
static constexpr int kD1  = 2048;
static constexpr int kD2  = 300;
static constexpr int kD2p = 320;       // K of p2 padded to multiple of 32
static constexpr int kATT = 1024;
static constexpr int kM   = kB * kP;   // 1568 rows of p1
static constexpr int kR2  = kB * kL;   // 640 rows of p2

// tanh(x) = 1 - 2/(exp2(x*2*log2(e)) + 1)   (exact at 0, saturates correctly)
__device__ __forceinline__ float fast_tanh(float x) {
    float e = __builtin_amdgcn_exp2f(x * 2.8853900817779268f);
    return 1.0f - 2.0f * __builtin_amdgcn_rcpf(e + 1.0f);
}

// fp32 -> bf16 round-to-nearest-even (inputs are finite; skip NaN path)
__device__ __forceinline__ unsigned short f2bf(float x) {
    union { float f; unsigned int u; } c; c.f = x;
    unsigned int r = c.u + 0x7fffu + ((c.u >> 16) & 1u);
    return (unsigned short)(r >> 16);
}

typedef __attribute__((ext_vector_type(8))) short  bf16x8;
typedef __attribute__((ext_vector_type(4))) float  f32x4;

__device__ __forceinline__ void load_lds16(const void* g, void* l) {
    __builtin_amdgcn_global_load_lds(
        (const __attribute__((address_space(1))) void*)g,
        (__attribute__((address_space(3))) void*)l, 16, 0, 0);
}

// ---------------------------------------------------------------------------
// Cast x1 (kM x kD1) and W1 (kATT x kD1) fp32 -> bf16, vectorized 4-wide.
// ---------------------------------------------------------------------------
__global__ __launch_bounds__(256) void cast_kernel(
        const float* __restrict__ x1, unsigned short* __restrict__ x1b,
        const float* __restrict__ W1, unsigned short* __restrict__ W1b) {
    const int n1 = kM * kD1 / 4;
    const int n2 = kATT * kD1 / 4;
    int i = blockIdx.x * 256 + threadIdx.x;
    if (i < n1) {
        float4 f = ((const float4*)x1)[i];
        ushort4 o = { f2bf(f.x), f2bf(f.y), f2bf(f.z), f2bf(f.w) };
        ((ushort4*)x1b)[i] = o;
    } else if (i - n1 < n2) {
        int j = i - n1;
        float4 f = ((const float4*)W1)[j];
        ushort4 o = { f2bf(f.x), f2bf(f.y), f2bf(f.z), f2bf(f.w) };
        ((ushort4*)W1b)[j] = o;
    }
}

// ---------------------------------------------------------------------------
// Cast+pad x2 (kR2 x 300 -> kR2 x 320) and W2 (kATT x 300 -> kATT x 320).
// Zero-fill cols 300..319 so the MFMA K-loop needs no edge handling.
// ---------------------------------------------------------------------------
__global__ __launch_bounds__(256) void cast_pad_kernel(
        const float* __restrict__ x2, unsigned short* __restrict__ x2b,
        const float* __restrict__ W2, unsigned short* __restrict__ W2b) {
    const int n1 = kR2 * kD2p;
    const int n2 = kATT * kD2p;
    int idx = blockIdx.x * 256 + threadIdx.x;
    if (idx < n1) {
        int r = idx / kD2p, c = idx - r * kD2p;
        x2b[idx] = (c < kD2) ? f2bf(x2[(size_t)r * kD2 + c]) : (unsigned short)0;
    } else if (idx - n1 < n2) {
        int j = idx - n1;
        int r = j / kD2p, c = j - r * kD2p;
        W2b[j] = (c < kD2) ? f2bf(W2[(size_t)r * kD2 + c]) : (unsigned short)0;
    }
}

// ---------------------------------------------------------------------------
// v[a] = sum_c wt[c]*Wh[c,a];  beta = dot(wt,bh) + bt
// ---------------------------------------------------------------------------
__global__ __launch_bounds__(256) void vbeta_kernel(
        const float* __restrict__ Wh, const float* __restrict__ wt,
        const float* __restrict__ bh, const float* __restrict__ bt,
        float* __restrict__ v, float* __restrict__ beta) {
    const int a  = blockIdx.x * 256 + threadIdx.x;
    const int c0 = blockIdx.y * 64;
    float acc = 0.0f;
    #pragma unroll 8
    for (int c = c0; c < c0 + 64; ++c)
        acc = fmaf(wt[c], Wh[(size_t)c * kATT + a], acc);
    atomicAdd(&v[a], acc);

    if (blockIdx.x == 0 && threadIdx.x < 64) {
        int c = c0 + threadIdx.x;
        float pb = wt[c] * bh[c];
        #pragma unroll
        for (int off = 32; off > 0; off >>= 1)
            pb += __shfl_down(pb, off, 64);
        if (threadIdx.x == 0) {
            if (blockIdx.y == 0) pb += bt[0];
            atomicAdd(beta, pb);
        }
    }
}

// ---------------------------------------------------------------------------
// C[m,n] = sum_k A[m,k]*B[n,k]  bf16 MFMA, 64x64 tile, BK=32, 4 waves.
// N fixed = kATT (1024). KT = K total (multiple of 32), row stride of A/B.
// Wave w computes the 32x32 quadrant (w>>1, w&1) as 2x2 MFMA 16x16 tiles.
// LDS: [row][k] k-major, 64B rows (global_load_lds lane-contiguous layout).
// ---------------------------------------------------------------------------
template<int KT>
__global__ __launch_bounds__(256) void gemm_bt_mfma(
        const unsigned short* __restrict__ Ab,
        const unsigned short* __restrict__ Bb,
        float* __restrict__ Co, int M) {
    __shared__ unsigned short As[64 * 32];   // 4 KB, row stride 64 B
    __shared__ unsigned short Bs[64 * 32];   // 4 KB
    const int m0   = blockIdx.x * 64;
    const int n0   = blockIdx.y * 64;
    const int tid  = threadIdx.x;
    const int lane = tid & 63;
    const int wv   = tid >> 6;
    const int mh   = (wv >> 1) * 32;
    const int nh   = (wv & 1) * 32;

    const int srow = tid >> 2;
    const int skc  = (tid & 3) * 8;
    const int arow = min(m0 + srow, M - 1);  // clamp ragged M edge
    const int brow = n0 + srow;              // N exact

    f32x4 acc[2][2] = {};
    for (int k0 = 0; k0 < KT; k0 += 32) {
        load_lds16(Ab + (size_t)arow * KT + k0 + skc, (char*)As + tid * 16);
        load_lds16(Bb + (size_t)brow * KT + k0 + skc, (char*)Bs + tid * 16);
        __syncthreads();

        bf16x8 af[2], bf[2];
        #pragma unroll
        for (int i = 0; i < 2; ++i) {
            int r = mh + i * 16 + (lane & 15);
            af[i] = *(const bf16x8*)((const char*)As + r * 64 + (lane >> 4) * 16);
        }
        #pragma unroll
        for (int j = 0; j < 2; ++j) {
            int r = nh + j * 16 + (lane & 15);
            bf[j] = *(const bf16x8*)((const char*)Bs + r * 64 + (lane >> 4) * 16);
        }
        #pragma unroll
        for (int i = 0; i < 2; ++i)
            #pragma unroll
            for (int j = 0; j < 2; ++j)
                acc[i][j] = __builtin_amdgcn_mfma_f32_16x16x32_bf16(
                                af[i], bf[j], acc[i][j], 0, 0, 0);
        __syncthreads();
    }

    // C/D layout: col = lane&15, row = (lane>>4)*4 + reg   [m89/m91 verified]
    #pragma unroll
    for (int i = 0; i < 2; ++i)
        #pragma unroll
        for (int j = 0; j < 2; ++j)
            #pragma unroll
            for (int r = 0; r < 4; ++r) {
                int m = m0 + mh + i * 16 + (lane >> 4) * 4 + r;
                int n = n0 + nh + j * 16 + (lane & 15);
                if (m < M) Co[(size_t)m * kATT + n] = acc[i][j][r];
            }
}

// ---------------------------------------------------------------------------
// alpha[b,l,p] = sum_a v[a]*tanh(p1[b,p,a]*p2[b,l,a]) + beta
// ---------------------------------------------------------------------------
__global__ __launch_bounds__(256) void alpha_kernel(
        const float* __restrict__ p1, const float* __restrict__ p2,
        const float* __restrict__ v, const float* __restrict__ beta,
        float* __restrict__ out) {
    __shared__ float vs[kATT];
    __shared__ float p1s[16 * 132];
    __shared__ float p2s[16 * 132];
    const int b   = blockIdx.z;
    const int p0  = blockIdx.x * 16;
    const int l0  = blockIdx.y * 16;
    const int tid = threadIdx.x;
    const int tp  = tid & 15;
    const int tl  = tid >> 4;

    for (int i = tid; i < kATT; i += 256) vs[i] = v[i];

    float acc = 0.0f;
    for (int a0 = 0; a0 < kATT; a0 += 128) {
        __syncthreads();
        #pragma unroll
        for (int t = 0; t < 2; ++t) {
            int idx = tid + t * 256;
            int row = idx >> 5;
            int c4  = (idx & 31) * 4;
            int gr1 = min(b * kP + p0 + row, kM - 1);
            float4 u = *(const float4*)(p1 + (size_t)gr1 * kATT + a0 + c4);
            *(float4*)&p1s[row * 132 + c4] = u;
            int gr2 = b * kL + l0 + row;
            float4 w = *(const float4*)(p2 + (size_t)gr2 * kATT + a0 + c4);
            *(float4*)&p2s[row * 132 + c4] = w;
        }
        __syncthreads();
        #pragma unroll
        for (int a4 = 0; a4 < 32; ++a4) {
            float4 u  = *(const float4*)&p1s[tp * 132 + a4 * 4];
            float4 w  = *(const float4*)&p2s[tl * 132 + a4 * 4];
            float4 vv = *(const float4*)&vs[a0 + a4 * 4];
            acc = fmaf(vv.x, fast_tanh(u.x * w.x), acc);
            acc = fmaf(vv.y, fast_tanh(u.y * w.y), acc);
            acc = fmaf(vv.z, fast_tanh(u.z * w.z), acc);
            acc = fmaf(vv.w, fast_tanh(u.w * w.w), acc);
        }
    }
    int p = p0 + tp;
    if (p < kP)
        out[((size_t)b * kL + l0 + tl) * kP + p] = acc + beta[0];
}

// ---------------------------------------------------------------------------
extern "C" void kernel_launch(void* const* d_in, const int* in_sizes, int n_in,
                              void* d_out, int out_size, void* d_ws, size_t ws_size,
                              hipStream_t stream) {
    const float* x1 = (const float*)d_in[0];
    const float* x2 = (const float*)d_in[1];
    const float* W1 = (const float*)d_in[2];
    const float* W2 = (const float*)d_in[3];
    const float* Wh = (const float*)d_in[4];
    const float* bh = (const float*)d_in[5];
    const float* wt = (const float*)d_in[6];
    const float* bt = (const float*)d_in[7];
    float* out = (float*)d_out;

    // workspace (floats then bf16):
    // v[1024] | beta pad -> 1088 | p2w[640*1024] | p1w[1568*1024]
    // | x1b[kM*kD1] | W1b[kATT*kD1] | x2b[kR2*320] | W2b[kATT*320]   (~20.7 MB)
    float* ws   = (float*)d_ws;
    float* v    = ws;
    float* beta = ws + 1024;
    float* p2w  = ws + 1088;
    float* p1w  = p2w + (size_t)kR2 * kATT;
    unsigned short* x1b = (unsigned short*)(p1w + (size_t)kM * kATT);
    unsigned short* W1b = x1b + (size_t)kM * kD1;
    unsigned short* x2b = W1b + (size_t)kATT * kD1;
    unsigned short* W2b = x2b + (size_t)kR2 * kD2p;

    hipMemsetAsync(ws, 0, 1088 * sizeof(float), stream);

    {   // cast x1 + W1 to bf16
        int n4 = (kM * kD1 + kATT * kD1) / 4;
        cast_kernel<<<dim3((n4 + 255) / 256), 256, 0, stream>>>(x1, x1b, W1, W1b);
    }
    {   // cast + pad x2 + W2 to bf16 (K 300 -> 320)
        int n = (kR2 + kATT) * kD2p;
        cast_pad_kernel<<<dim3((n + 255) / 256), 256, 0, stream>>>(x2, x2b, W2, W2b);
    }
    vbeta_kernel<<<dim3(4, 16), 256, 0, stream>>>(Wh, wt, bh, bt, v, beta);
    gemm_bt_mfma<kD2p><<<dim3(kR2 / 64, kATT / 64), 256, 0, stream>>>(x2b, W2b, p2w, kR2);
    gemm_bt_mfma<kD1><<<dim3((kM + 63) / 64, kATT / 64), 256, 0, stream>>>(x1b, W1b, p1w, kM);
    alpha_kernel<<<dim3((kP + 15) / 16, kL / 16, kB), 256, 0, stream>>>(p1w, p2w, v, beta, out);
}